// Round 7
// baseline (421.948 us; speedup 1.0000x reference)
//
#include <hip/hip_runtime.h>
#include <hip/hip_bf16.h>
#include <math.h>
#include <stdint.h>

constexpr int Bn = 64, Nn = 1024, Hn = 64;
constexpr float LRELU_ALPHA = 0.2f;

typedef __attribute__((ext_vector_type(8))) short bf16x8;   // MFMA A/B frag (4 VGPR)
typedef __attribute__((ext_vector_type(4))) float f32x4;    // MFMA C/D frag

__device__ __forceinline__ float lrelu(float x) { return x >= 0.f ? x : LRELU_ALPHA * x; }
// RNE float->bf16 (finite, non-negative inputs here; f2bf(0)==0 exactly)
__device__ __forceinline__ ushort f2bf(float x) {
    uint u = __float_as_uint(x);
    return (ushort)((u + 0x7FFFu + ((u >> 16) & 1u)) >> 16);
}
__device__ __forceinline__ float bf2f(ushort b) { return __uint_as_float(((uint)b) << 16); }

// Barrier that does NOT drain vmcnt. lgkmcnt(0) makes this wave's ds_writes
// visible before others pass the barrier; "memory" clobbers pin ordering.
#define LDS_BARRIER()                                             \
    do {                                                          \
        asm volatile("s_waitcnt lgkmcnt(0)" ::: "memory");        \
        __builtin_amdgcn_s_barrier();                             \
        asm volatile("" ::: "memory");                            \
    } while (0)

// ---------------------------------------------------------------------------
// Kernel 0: compress binary A (fp32 0/1) -> bitmask, 32x smaller.
// bm word W covers flat floats [W*32, W*32+32), bit k <-> flat index W*32+k.
// Pure stream: no LDS, no barriers -> should run at ~HBM peak.
// Thread: 8 floats -> 1 byte; 4 lanes pack -> 1 uint via shfl_xor.
// ---------------------------------------------------------------------------
__global__ __launch_bounds__(256) void amask_kernel(const float* __restrict__ A,
                                                    uint* __restrict__ bm)
{
    const size_t g = (size_t)blockIdx.x * 256 + threadIdx.x;   // byte index
    const int lane = threadIdx.x & 63;
    const float4 v0 = *(const float4*)(A + g * 8);
    const float4 v1 = *(const float4*)(A + g * 8 + 4);
    uint b = 0;
    b |= (v0.x > 0.f) ? 1u   : 0u;
    b |= (v0.y > 0.f) ? 2u   : 0u;
    b |= (v0.z > 0.f) ? 4u   : 0u;
    b |= (v0.w > 0.f) ? 8u   : 0u;
    b |= (v1.x > 0.f) ? 16u  : 0u;
    b |= (v1.y > 0.f) ? 32u  : 0u;
    b |= (v1.z > 0.f) ? 64u  : 0u;
    b |= (v1.w > 0.f) ? 128u : 0u;
    uint t = b | (__shfl_xor(b, 1) << 8);    // lane0: b0|b1<<8; lane2: b2|b3<<8
    uint u = t | (__shfl_xor(t, 2) << 16);   // lane0: b0..b3 packed
    if ((lane & 3) == 0) bm[g >> 2] = u;
}

// ---------------------------------------------------------------------------
// Kernel 1 (prep): fused transpose/convert + Wh1/Wh2.
// ---------------------------------------------------------------------------
__global__ __launch_bounds__(256) void prep_kernel(
    const float* __restrict__ inp, const float* __restrict__ inp_none,
    const int* __restrict__ l, const float* __restrict__ a_i,
    const float* __restrict__ a_c,
    ushort* __restrict__ inpT, float* __restrict__ Wh1, float* __restrict__ Wh2)
{
    __shared__ ushort tile[64][74];
    const int b  = blockIdx.x >> 4;
    const int q0 = (blockIdx.x & 15) << 6;
    const int t  = threadIdx.x;
    const int l0 = l[b * 2], l1 = l[b * 2 + 1];

    {
        const int q    = t >> 2;          // 0..63 tile row
        const int h0   = (t & 3) << 4;    // 0,16,32,48
        const int grow = q0 + q;
        const bool in_range = (grow >= l0) && (grow < l1);

        const float* src  = inp + ((size_t)(b * Nn + grow) * Hn + h0);
        const float* av2p = (in_range ? a_i : a_c) + Hn + h0;
        uint* dst = (uint*)&tile[q][h0];

        float p1 = 0.f, p2 = 0.f;
        #pragma unroll
        for (int i = 0; i < 4; ++i) {
            const float4 v = *(const float4*)(src + 4 * i);
            dst[2 * i + 0] = (uint)f2bf(v.x) | ((uint)f2bf(v.y) << 16);
            dst[2 * i + 1] = (uint)f2bf(v.z) | ((uint)f2bf(v.w) << 16);
            const float4 a2 = *(const float4*)(av2p + 4 * i);
            p2 += (v.x * a2.x + v.y * a2.y) + (v.z * a2.z + v.w * a2.w);
        }
        if (in_range) {
            const float* s1 = inp_none + ((size_t)(b * Nn + grow) * Hn + h0);
            #pragma unroll
            for (int i = 0; i < 4; ++i) {
                const float4 v1 = *(const float4*)(s1 + 4 * i);
                const float4 a1 = *(const float4*)(a_i + h0 + 4 * i);
                p1 += (v1.x * a1.x + v1.y * a1.y) + (v1.z * a1.z + v1.w * a1.w);
            }
        } else {
            const float* s1 = inp + ((size_t)(b * Nn + grow) * Hn + h0);
            #pragma unroll
            for (int i = 0; i < 4; ++i) {
                const float4 v1 = *(const float4*)(s1 + 4 * i);
                const float4 a1 = *(const float4*)(a_c + h0 + 4 * i);
                p1 += (v1.x * a1.x + v1.y * a1.y) + (v1.z * a1.z + v1.w * a1.w);
            }
        }
        p1 += __shfl_xor(p1, 1); p1 += __shfl_xor(p1, 2);
        p2 += __shfl_xor(p2, 1); p2 += __shfl_xor(p2, 2);
        if ((t & 3) == 0) {
            Wh1[b * Nn + grow] = p1;
            Wh2[b * Nn + grow] = p2;
        }
    }
    __syncthreads();
    {
        const int h  = t >> 2;           // 0..63
        const int qb = (t & 3) << 4;     // 0,16,32,48
        uint w[8];
        #pragma unroll
        for (int i = 0; i < 8; ++i)
            w[i] = (uint)tile[qb + 2 * i][h] | ((uint)tile[qb + 2 * i + 1][h] << 16);
        uint4* dst = (uint4*)(inpT + ((size_t)(b * Hn + h) * Nn + q0 + qb));
        dst[0] = make_uint4(w[0], w[1], w[2], w[3]);
        dst[1] = make_uint4(w[4], w[5], w[6], w[7]);
    }
}

// select word j (compile-time j under unroll) from two uint4
__device__ __forceinline__ uint jw(const uint4& W0, const uint4& W1, int j) {
    return (j == 0) ? W0.x : (j == 1) ? W0.y : (j == 2) ? W0.z : (j == 3) ? W0.w
         : (j == 4) ? W1.x : (j == 5) ? W1.y : (j == 6) ? W1.z : W1.w;
}

// ---------------------------------------------------------------------------
// Kernel 2 (main): exp-weights from BITMASK + MFMA aggregation + ELU.
// Block = 256 thr (4 waves), 32 p-rows of one batch. Mask bits for chunk c+1
// are prefetched into 8 VGPRs during chunk c. No A stream, no spill pressure.
//
// SWIZZLE RULE (round-4 NaN bug): address = row*512 + (col ^ swz), col<512.
// Never XOR a base then ADD a col stride overlapping swizzle bits.
// ---------------------------------------------------------------------------
__global__ __launch_bounds__(256, 4) void gat_mfma_kernel(
    const uint* __restrict__ bm, const ushort* __restrict__ inpT,
    const float* __restrict__ Wh1, const float* __restrict__ Wh2,
    float* __restrict__ out)
{
    // [0,16384) w bf16 [32][256] swizzled (aliased later by out_lds [32][65] f32)
    // [16384,20480) wh2 f32[1024] (aliased later by rs_part/inv after last use)
    // exactly 20 KB -> 8 blocks/CU.
    __shared__ __align__(16) char pool[20480];
    float* wh2_lds = (float*)(pool + 16384);
    float* rs_part = (float*)(pool + 16384);          // alias: used after wh2 done
    float* inv_lds = (float*)(pool + 16384 + 1024);   // alias, disjoint from rs_part
    float* out_lds = (float*)pool;

    const int t    = threadIdx.x;
    const int wave = t >> 6;
    const int lane = t & 63;

    // XCD swizzle: 2048 blocks, 256/XCD => 8 batches per XCD, inpT[b] L2-hot
    const int d = blockIdx.x;
    const int o = (d & 7) * 256 + (d >> 3);
    const int b  = o >> 5;
    const int p0 = (o & 31) << 5;

    const float*  Wh2b = Wh2 + b * Nn;
    const ushort* Tb   = inpT + (size_t)b * Hn * Nn;

    // score-pass mapping: thread -> (row r, 4-q group u)
    const int r = t >> 3;                        // 0..31
    const int u = t & 7;                         // q = c*256 + 32j + u*4 + cc
    const float wh1_r = Wh1[b * Nn + p0 + r];
    const uint* bmrow = bm + (size_t)(b * Nn + p0 + r) * 32;

    // MFMA mapping
    const int l15 = lane & 15;
    const int lg  = lane >> 4;                   // 0..3
    const ushort* a_src = Tb + (size_t)(wave * 16 + l15) * Nn + lg * 8;
    const uint bswz = ((uint)(l15 & 7)) << 4;    // swizzle bits 4-6
    const uint row0 = (uint)(l15 * 512);
    const uint row1 = (uint)((l15 + 16) * 512);

    // ---- prologue: chunk-0 mask words + wh2 full preload ----
    uint4 W0 = *(const uint4*)(bmrow);
    uint4 W1 = *(const uint4*)(bmrow + 4);
    #pragma unroll
    for (int w = 0; w < 4; ++w) wh2_lds[w * 256 + t] = Wh2b[w * 256 + t];
    LDS_BARRIER();   // wh2 visible; mask loads still in flight (consumed below)

    f32x4 acc0 = {0.f, 0.f, 0.f, 0.f};
    f32x4 acc1 = {0.f, 0.f, 0.f, 0.f};
    float rs_local = 0.f;

    #pragma unroll
    for (int c = 0; c < 4; ++c) {
        // ---- score pass: mask bits + wh2 -> swizzled bf16 w in LDS ----
        #pragma unroll
        for (int j = 0; j < 8; ++j) {
            const uint nib = (jw(W0, W1, j) >> (u * 4)) & 15u;
            const int  qq  = u * 4 + 32 * j;     // chunk-relative q
            const float4 w2 = *(const float4*)(wh2_lds + c * 256 + qq);
            const float e0 = __expf(lrelu(wh1_r + w2.x));
            const float e1 = __expf(lrelu(wh1_r + w2.y));
            const float e2 = __expf(lrelu(wh1_r + w2.z));
            const float e3 = __expf(lrelu(wh1_r + w2.w));
            const ushort u0 = (nib & 1u) ? f2bf(e0) : (ushort)0;
            const ushort u1 = (nib & 2u) ? f2bf(e1) : (ushort)0;
            const ushort u2 = (nib & 4u) ? f2bf(e2) : (ushort)0;
            const ushort u3 = (nib & 8u) ? f2bf(e3) : (ushort)0;
            // rowsum over bf16-ROUNDED weights (normalization cancels rounding)
            rs_local += (bf2f(u0) + bf2f(u1)) + (bf2f(u2) + bf2f(u3));
            const uint lo = (uint)u0 | ((uint)u1 << 16);
            const uint hi = (uint)u2 | ((uint)u3 << 16);
            const uint byte = ((uint)(r * 512 + qq * 2)) ^ (((uint)(r & 7)) << 4);
            *(uint2*)(pool + byte) = make_uint2(lo, hi);
        }
        // ---- prefetch chunk c+1 mask words (in flight across MFMA) ----
        if (c < 3) {
            W0 = *(const uint4*)(bmrow + (c + 1) * 8);
            W1 = *(const uint4*)(bmrow + (c + 1) * 8 + 4);
        }
        LDS_BARRIER();   // w ready (lgkm only; vm loads keep flying)

        // ---- MFMA: D[h][p] += inpT[h][k] * w[p][k], 8 ksteps of 32 ----
        #pragma unroll
        for (int kk = 0; kk < 8; ++kk) {
            const uint col = ((uint)(lg * 16 + kk * 64)) ^ bswz;  // col<512
            const bf16x8 af = *(const bf16x8*)(a_src + c * 256 + kk * 32);
            const bf16x8 b0 = *(const bf16x8*)(pool + (row0 + col));
            const bf16x8 b1 = *(const bf16x8*)(pool + (row1 + col));
            acc0 = __builtin_amdgcn_mfma_f32_16x16x32_bf16(af, b0, acc0, 0, 0, 0);
            acc1 = __builtin_amdgcn_mfma_f32_16x16x32_bf16(af, b1, acc1, 0, 0, 0);
        }
        LDS_BARRIER();   // all w readers done before next overwrite
    }

    // ---- rowsum reduce + inverse (rs_part aliases wh2 region, now dead) ----
    rs_part[t] = rs_local;      // t == r*8 + u
    __syncthreads();
    if (t < 32) {
        float s = 0.f;
        #pragma unroll
        for (int j = 0; j < 8; ++j) s += rs_part[t * 8 + j];
        inv_lds[t] = s > 0.f ? 1.f / s : 0.f;
    }
    __syncthreads();

    // ---- normalize into out_lds[32][65] (aliases w region; reads done) ----
    #pragma unroll
    for (int nt = 0; nt < 2; ++nt) {
        const int p = nt * 16 + l15;
        const float inv = inv_lds[p];
        const f32x4 a = nt ? acc1 : acc0;
        #pragma unroll
        for (int rg = 0; rg < 4; ++rg) {
            const int h = wave * 16 + lg * 4 + rg;   // m89-verified C/D layout
            out_lds[p * 65 + h] = a[rg] * inv;
        }
    }
    __syncthreads();

    // ---- ELU + coalesced store ----
    {
        const int p  = t >> 3;
        const int h0 = (t & 7) << 3;
        float v[8];
        #pragma unroll
        for (int i = 0; i < 8; ++i) {
            const float x = out_lds[p * 65 + h0 + i];
            v[i] = x > 0.f ? x : expm1f(x);
        }
        float* orow = out + (size_t)(b * Nn + p0 + p) * Hn + h0;
        *(float4*)(orow)     = make_float4(v[0], v[1], v[2], v[3]);
        *(float4*)(orow + 4) = make_float4(v[4], v[5], v[6], v[7]);
    }
}

// ---------------------------------------------------------------------------
// Fallback path (ws too small): round-3 kernels, known-good, A read directly.
// ---------------------------------------------------------------------------
__global__ __launch_bounds__(256) void wh_kernel(
    const float* __restrict__ inp, const float* __restrict__ inp_none,
    const int* __restrict__ l, const float* __restrict__ a_i,
    const float* __restrict__ a_c,
    float* __restrict__ Wh1, float* __restrict__ Wh2)
{
    const int wave = threadIdx.x >> 6;
    const int lane = threadIdx.x & 63;
    const int row  = blockIdx.x * 4 + wave;
    const int b    = row >> 10;
    const int n    = row & (Nn - 1);
    const int l0 = l[b * 2], l1 = l[b * 2 + 1];
    const bool in_range = (n >= l0) && (n < l1);
    const size_t base = (size_t)row * Hn + lane;
    const float x1  = in_range ? inp_none[base] : inp[base];
    const float x2  = inp[base];
    const float av1 = in_range ? a_i[lane]      : a_c[lane];
    const float av2 = in_range ? a_i[Hn + lane] : a_c[Hn + lane];
    float p1 = x1 * av1;
    float p2 = x2 * av2;
    #pragma unroll
    for (int off = 32; off > 0; off >>= 1) {
        p1 += __shfl_xor(p1, off);
        p2 += __shfl_xor(p2, off);
    }
    if (lane == 0) { Wh1[row] = p1; Wh2[row] = p2; }
}

__global__ __launch_bounds__(256) void gat_fallback_kernel(
    const float* __restrict__ inp, const float* __restrict__ A,
    const float* __restrict__ Wh1, const float* __restrict__ Wh2,
    float* __restrict__ out)
{
    __shared__ float wlds[4][256];
    __shared__ int   qlds[4][256];
    const int wave = threadIdx.x >> 6;
    const int lane = threadIdx.x & 63;
    const int cpx = gridDim.x >> 3;
    const int bid = blockIdx.x;
    const int swz = (bid & 7) * cpx + (bid >> 3);
    const int row = swz * 4 + wave;
    const int b   = row >> 10;
    const int p   = row & (Nn - 1);
    const float* Arow = A + ((size_t)b * Nn + p) * Nn;
    const float* Wh2b = Wh2 + b * Nn;
    const float  wh1p = Wh1[b * Nn + p];
    float4 sv[4];
    float  m = -INFINITY;
    #pragma unroll
    for (int k = 0; k < 4; ++k) {
        const int q0 = k * 256 + lane * 4;
        const float4 a4 = *(const float4*)(Arow + q0);
        const float4 w2 = *(const float4*)(Wh2b + q0);
        float4 s;
        s.x = (a4.x > 0.f) ? lrelu(wh1p + w2.x) : -INFINITY;
        s.y = (a4.y > 0.f) ? lrelu(wh1p + w2.y) : -INFINITY;
        s.z = (a4.z > 0.f) ? lrelu(wh1p + w2.z) : -INFINITY;
        s.w = (a4.w > 0.f) ? lrelu(wh1p + w2.w) : -INFINITY;
        sv[k] = s;
        m = fmaxf(m, fmaxf(fmaxf(s.x, s.y), fmaxf(s.z, s.w)));
    }
    #pragma unroll
    for (int off = 32; off > 0; off >>= 1) m = fmaxf(m, __shfl_xor(m, off));
    const bool empty = (m == -INFINITY);
    const float* inpb = inp + (size_t)b * Nn * Hn;
    float acc0 = 0.f, acc1 = 0.f;
    if (!empty) {
        float4 wv[4];
        float  lsum = 0.f;
        #pragma unroll
        for (int k = 0; k < 4; ++k) {
            float4 s = sv[k];
            float4 w;
            w.x = __expf(s.x - m); w.y = __expf(s.y - m);
            w.z = __expf(s.z - m); w.w = __expf(s.w - m);
            wv[k] = w;
            lsum += (w.x + w.y) + (w.z + w.w);
        }
        #pragma unroll
        for (int off = 32; off > 0; off >>= 1) lsum += __shfl_xor(lsum, off);
        const float inv = 1.f / lsum;
        int c = 0;
        #pragma unroll
        for (int k = 0; k < 4; ++k)
            #pragma unroll
            for (int cc = 0; cc < 4; ++cc)
                c += (((const float*)&wv[k])[cc] != 0.f) ? 1 : 0;
        int s = c;
        #pragma unroll
        for (int off = 1; off < 64; off <<= 1) {
            const int tt = __shfl_up(s, off);
            if (lane >= off) s += tt;
        }
        int j   = s - c;
        int cnt = __shfl(s, 63);
        #pragma unroll
        for (int k = 0; k < 4; ++k)
            #pragma unroll
            for (int cc = 0; cc < 4; ++cc) {
                const float w = ((const float*)&wv[k])[cc];
                if (w != 0.f && j < 256) {
                    wlds[wave][j] = w;
                    qlds[wave][j] = (k * 256 + lane * 4 + cc) * Hn;
                    ++j;
                }
            }
        if (cnt > 256) cnt = 256;
        asm volatile("s_waitcnt lgkmcnt(0)" ::: "memory");
        int i = 0;
        for (; i + 4 <= cnt; i += 4) {
            const float w0 = wlds[wave][i], w1 = wlds[wave][i + 1];
            const float w2 = wlds[wave][i + 2], w3 = wlds[wave][i + 3];
            const int o0 = qlds[wave][i], o1 = qlds[wave][i + 1];
            const int o2 = qlds[wave][i + 2], o3 = qlds[wave][i + 3];
            acc0 = fmaf(w0, inpb[o0 + lane], acc0);
            acc1 = fmaf(w1, inpb[o1 + lane], acc1);
            acc0 = fmaf(w2, inpb[o2 + lane], acc0);
            acc1 = fmaf(w3, inpb[o3 + lane], acc1);
        }
        for (; i < cnt; ++i)
            acc0 = fmaf(wlds[wave][i], inpb[qlds[wave][i] + lane], acc0);
        acc0 = (acc0 + acc1) * inv;
    } else {
        for (int q = 0; q < Nn; ++q) acc0 += inpb[q * Hn + lane];
        acc0 *= (1.f / Nn);
    }
    const float rr = acc0 > 0.f ? acc0 : expm1f(acc0);
    out[(size_t)row * Hn + lane] = rr;
}

// ---------------------------------------------------------------------------
extern "C" void kernel_launch(void* const* d_in, const int* in_sizes, int n_in,
                              void* d_out, int out_size, void* d_ws, size_t ws_size,
                              hipStream_t stream) {
    const float* inp      = (const float*)d_in[0];
    const float* inp_none = (const float*)d_in[1];
    const float* A        = (const float*)d_in[2];
    const int*   l        = (const int*)d_in[3];
    const float* a_i      = (const float*)d_in[4];
    const float* a_c      = (const float*)d_in[5];
    float* out = (float*)d_out;

    char* ws = (char*)d_ws;
    float*  Wh1  = (float*)ws;                                   // 256 KB
    float*  Wh2  = (float*)(ws + (size_t)Bn * Nn * 4);           // 256 KB
    ushort* inpT = (ushort*)(ws + (size_t)2 * Bn * Nn * 4);      // 8 MB bf16
    uint*   bmp  = (uint*)(ws + (size_t)2 * Bn * Nn * 4 + (size_t)Bn * Hn * Nn * 2);  // 8 MB

    const size_t need = (size_t)2 * Bn * Nn * 4 + (size_t)Bn * Hn * Nn * 2
                      + (size_t)Bn * Nn * (Nn / 8);

    if (ws_size >= need) {
        amask_kernel<<<Bn * Nn * Nn / 8 / 256, 256, 0, stream>>>(A, bmp);
        prep_kernel<<<Bn * 16, 256, 0, stream>>>(inp, inp_none, l, a_i, a_c,
                                                 inpT, Wh1, Wh2);
        gat_mfma_kernel<<<Bn * 32, 256, 0, stream>>>(bmp, inpT, Wh1, Wh2, out);
    } else {
        wh_kernel<<<Bn * Nn / 4, 256, 0, stream>>>(inp, inp_none, l, a_i, a_c, Wh1, Wh2);
        gat_fallback_kernel<<<Bn * Nn / 4, 256, 0, stream>>>(inp, A, Wh1, Wh2, out);
    }
}